// Round 4
// baseline (313.091 us; speedup 1.0000x reference)
//
#include <hip/hip_runtime.h>
#include <math.h>

// CFE hydrologic scan (R4): latency attack.
//  - forcing prefetch ring deepened to 4 steps (register rotation) to cover
//    L3/HBM latency; every wave's 32B/step is private -> no cross-wave reuse.
//  - dependent chain shortened algebraically:
//      * asc = min(above*sc_const, above^2/NZ)  (exact rewrite; kills a rcp)
//      * budyko = clamp(fma(soil,k1,k2))
//      * invariant-backed clamp removals (q_gw>=0, gw>=NZ, soil>=NZ)
//      * Nash with precomputed (1-K), fma chain
//  - DPP16 m-reduction stays pipelined one step behind (off-chain).

constexpr int T_STEPS = 730;
constexpr int BATCH   = 2048;
constexpr int NMULC   = 16;
constexpr int LENFC   = 15;
constexpr int NPHYS   = 13;
constexpr int NSTAT   = NPHYS * NMULC + 2; // 210
constexpr float NZ    = 1e-5f;

__device__ __forceinline__ float frcp(float x) { return __builtin_amdgcn_rcpf(x); }

// 16-lane sum via DPP16 row ops; all lanes end with the group sum. No LDS.
__device__ __forceinline__ float dpp_sum16(float x) {
    int v;
    v = __builtin_amdgcn_update_dpp(0, __float_as_int(x), 0xB1, 0xF, 0xF, true); // quad_perm(1,0,3,2)
    x += __int_as_float(v);
    v = __builtin_amdgcn_update_dpp(0, __float_as_int(x), 0x4E, 0xF, 0xF, true); // quad_perm(2,3,0,1)
    x += __int_as_float(v);
    v = __builtin_amdgcn_update_dpp(0, __float_as_int(x), 0x141, 0xF, 0xF, true); // row_half_mirror
    x += __int_as_float(v);
    v = __builtin_amdgcn_update_dpp(0, __float_as_int(x), 0x140, 0xF, 0xF, true); // row_mirror
    x += __int_as_float(v);
    return x;
}

__global__ __launch_bounds__(64, 1)
void cfe_kernel(const float* __restrict__ x,   // (T,B,2)
                const float* __restrict__ ps,  // (B,NSTAT)
                float* __restrict__ out)       // (T,B)
{
    const int tid = blockIdx.x * 64 + threadIdx.x;
    const int b   = tid >> 4;
    const int m   = tid & 15;
    if (b >= BATCH) return;

    const float* __restrict__ row = ps + b * NSTAT;

    // ---- parameter de-normalization ------------------------------------
    const float schaake    = row[ 0*NMULC + m] * 0.1f;
    const float smcmax     = row[ 1*NMULC + m] * 0.3f   + 0.3f;
    const float soil_depth = row[ 2*NMULC + m] * 2.5f   + 0.5f;
    const float wltsmc     = row[ 3*NMULC + m] * 0.15f  + 0.05f;
    const float satpsi     = row[ 4*NMULC + m] * 0.49f  + 0.01f;
    const float bb         = row[ 5*NMULC + m] * 10.0f  + 2.0f;
    const float multp      = row[ 6*NMULC + m] * 1900.0f+ 100.0f;
    const float satdk      = row[ 7*NMULC + m] * (1e-4f - 1e-7f) + 1e-7f;
    const float slop       = row[ 8*NMULC + m];
    const float max_gw     = row[ 9*NMULC + m] * 0.49f  + 0.01f;
    const float Cgw        = row[10*NMULC + m] * (1e-3f - 1e-6f) + 1e-6f;
    const float expon      = row[11*NMULC + m] * 7.0f   + 1.0f;
    const float K          = row[12*NMULC + m] * 0.49f  + 0.01f;

    const float rout_a = row[NPHYS*NMULC + 0] * 2.9f;
    const float rout_b = row[NPHYS*NMULC + 1] * 6.5f;

    // ---- derived per-chain constants -----------------------------------
    const float inv_sd   = 1.0f / soil_depth;
    const float bud_den  = 1.0f / (smcmax - wltsmc + NZ);
    const float k1       = inv_sd * bud_den;        // budyko = clamp(fma(soil,k1,k2))
    const float k2       = -wltsmc * bud_den;
    const float max_soil = smcmax * soil_depth;
    float fc_frac = powf(satpsi * inv_sd, 1.0f / bb);
    fc_frac = fminf(fmaxf(fc_frac, 0.0f), 1.0f);
    const float fc_th    = smcmax * fc_frac * soil_depth;
    const float ic       = 1.0f - expf(-schaake);
    const float sm       = satdk * multp;
    const float sml      = sm * slop;
    const float inv_mft  = 1.0f / fmaxf(max_soil - fc_th, NZ);
    const float inv_mgw  = 1.0f / max_gw;
    const float cc       = inv_mft * (sm + sml);    // tot  = cc*above
    const float pc       = sm  * inv_mft;           // perc = pc*asc
    const float lc       = sml * inv_mft;           // lat  = lc*asc
    const float sc_const = fminf(1.0f, 1.0f / cc);  // exact scale rewrite
    const float inv_nz   = 1.0f / NZ;
    const float e2       = expon * 1.442695041f;    // expon*log2(e)
    const float Km       = 1.0f - K;

    // ---- routing weights (lgamma/th^a cancel; fold 1/16 mean) ----------
    const float a  = fmaxf(rout_a, 0.0f) + 0.1f;
    const float th = fmaxf(rout_b, 0.0f) + 0.5f;
    float w[LENFC];
    float wsum = 0.0f;
    #pragma unroll
    for (int j = 0; j < LENFC; ++j) {
        const float tj = (float)j + 0.5f;
        w[j] = powf(tj, a - 1.0f) * expf(-tj / th);
        wsum += w[j];
    }
    const float wscale = 1.0f / (wsum * (float)NMULC);
    #pragma unroll
    for (int j = 0; j < LENFC; ++j) w[j] *= wscale;

    // ---- state ----------------------------------------------------------
    float soil = 0.05f, gw = 0.01f;
    float n0 = NZ, n1 = NZ, n2 = NZ;
    float ring[LENFC];
    #pragma unroll
    for (int j = 0; j < LENFC; ++j) ring[j] = 0.0f;

    const float2* __restrict__ xp = (const float2*)x;

    // ---- forcing prefetch ring, depth 4 ---------------------------------
    float2 fb0 = xp[0 * BATCH + b];
    float2 fb1 = xp[1 * BATCH + b];
    float2 fb2 = xp[2 * BATCH + b];
    float2 fb3 = xp[3 * BATCH + b];

    float s_prev = 0.0f;

    for (int t = 0; t < T_STEPS; ++t) {
        // ---- pipelined DPP reduction + store for step t-1 (off-chain) ---
        {
            const float r = dpp_sum16(s_prev);
            if (t > 0 && m == 0) out[(t - 1) * BATCH + b] = r;
        }

        const float p   = fb0.x;
        const float pet = fb0.y;
        fb0 = fb1; fb1 = fb2; fb2 = fb3;
        const int tn = (t + 4 < T_STEPS) ? (t + 4) : (T_STEPS - 1);
        fb3 = xp[tn * BATCH + b];

        // -- off-chain precompute (depends only on p,pet: ready 4 steps early)
        const float et_rain = fminf(p, pet);
        const float p_rem   = p - et_rain;
        const float pet_rem = pet - et_rain;
        const float prem_nz = p_rem + NZ;
        const float prem_sq = p_rem * p_rem;

        // -- soil ET (budyko folded to one fma + clamp)
        float budyko = fmaf(soil, k1, k2);
        budyko = fminf(fmaxf(budyko, 0.0f), 1.0f);
        const float aet_soil = fminf(pet_rem * budyko, soil - NZ); // soil>=NZ invariant
        soil -= aet_soil;

        // -- Schaake partitioning
        const float deficit = max_soil - soil;                 // soil<=max_soil invariant
        const float den     = fmaf(deficit, ic, prem_nz);      // p_rem + infil_cap + NZ
        const float runoff0 = prem_sq * frcp(den);
        const float infiltration = fminf(p_rem - runoff0, deficit);
        const float runoff  = p_rem - infiltration;
        soil += infiltration;

        // -- percolation / lateral: exact rewrite of the scale clamp
        const float above = fmaxf(soil - fc_th, 0.0f);
        const float asc   = fminf(above * sc_const, above * above * inv_nz);
        const float lat   = lc * asc;
        soil = fmaf(-cc, asc, soil);                           // -(perc+lat)

        // -- groundwater (exp2; q_gw>=0 and gw>=NZ invariants)
        gw = fmaf(pc, asc, gw);
        const float ratio = fminf(gw * inv_mgw, 1.0f);         // gw>0 invariant
        const float q_gw0 = fmaf(Cgw, __builtin_amdgcn_exp2f(e2 * ratio), -Cgw);
        const float q_gw  = fminf(q_gw0, gw - NZ);
        gw -= q_gw;

        // -- Nash cascade (Km = 1-K precomputed)
        const float s0 = n0 + lat;          const float s1 = fmaf(K, s0, n1);
        const float s2 = fmaf(K, s1, n2);   const float o2 = K * s2;
        n0 = Km * s0; n1 = Km * s1; n2 = Km * s2;

        const float q = runoff + o2 + q_gw;   // lane-local, NOT reduced

        // -- 15-tap conv on lane-local history (treed)
        #pragma unroll
        for (int j = LENFC - 1; j > 0; --j) ring[j] = ring[j - 1];
        ring[0] = q;
        float c0 = 0.0f, c1 = 0.0f, c2 = 0.0f, c3 = 0.0f;
        #pragma unroll
        for (int j = 0; j < LENFC; j += 4) {
            c0 = fmaf(w[j], ring[j], c0);
            if (j + 1 < LENFC) c1 = fmaf(w[j + 1], ring[j + 1], c1);
            if (j + 2 < LENFC) c2 = fmaf(w[j + 2], ring[j + 2], c2);
            if (j + 3 < LENFC) c3 = fmaf(w[j + 3], ring[j + 3], c3);
        }
        s_prev = (c0 + c1) + (c2 + c3);
    }

    // ---- epilogue --------------------------------------------------------
    {
        const float r = dpp_sum16(s_prev);
        if (m == 0) out[(T_STEPS - 1) * BATCH + b] = r;
    }
}

extern "C" void kernel_launch(void* const* d_in, const int* in_sizes, int n_in,
                              void* d_out, int out_size, void* d_ws, size_t ws_size,
                              hipStream_t stream) {
    const float* x_phy      = (const float*)d_in[0];
    const float* phy_static = (const float*)d_in[1];
    float* out = (float*)d_out;

    const int total = BATCH * NMULC;            // 32768 threads
    const int block = 64;
    const int grid  = total / block;            // 512 blocks
    cfe_kernel<<<grid, block, 0, stream>>>(x_phy, phy_static, out);
}

// Round 5
// 181.402 us; speedup vs baseline: 1.7260x; 1.7260x over previous
//
#include <hip/hip_runtime.h>
#include <math.h>

// CFE hydrologic scan (R5): ILP attack.
// Each thread now owns TWO m-chains of the SAME basin (m and m+8):
//  - 8 lanes per basin, 16384 threads = 256 waves, 1 block/CU on all 256 CUs
//  - the two independent chain bodies interleave in the issue stream and
//    fill each other's dependency stalls (we measured ~600 stall cyc/step
//    with a single chain per thread)
//  - conv is linear and the gamma weights are per-basin: sum the two chains'
//    q BEFORE the ring -> one ring, one 15-tap conv, one reduction
//  - m-reduction is now 3 DPP stages over the 8-lane group, still pipelined
//    one step behind the recurrence
//  - forcing: one float2 load per thread per step; a wave covers 8
//    consecutive basins = one 64B line per step

constexpr int T_STEPS = 730;
constexpr int BATCH   = 2048;
constexpr int NMULC   = 16;
constexpr int LENFC   = 15;
constexpr int NPHYS   = 13;
constexpr int NSTAT   = NPHYS * NMULC + 2; // 210
constexpr float NZ    = 1e-5f;
constexpr int NCH     = 2;                 // m-chains per thread
constexpr int LPB     = 8;                 // lanes per basin

__device__ __forceinline__ float frcp(float x) { return __builtin_amdgcn_rcpf(x); }

// 8-lane group sum via DPP: xor1, xor2, then cross-quad (row_half_mirror:
// l -> l^7 within each 8-lane half-row; valid since quads are uniform by then).
__device__ __forceinline__ float dpp_sum8(float x) {
    int v;
    v = __builtin_amdgcn_update_dpp(0, __float_as_int(x), 0xB1, 0xF, 0xF, true);  // quad_perm(1,0,3,2)
    x += __int_as_float(v);
    v = __builtin_amdgcn_update_dpp(0, __float_as_int(x), 0x4E, 0xF, 0xF, true);  // quad_perm(2,3,0,1)
    x += __int_as_float(v);
    v = __builtin_amdgcn_update_dpp(0, __float_as_int(x), 0x141, 0xF, 0xF, true); // row_half_mirror
    x += __int_as_float(v);
    return x;
}

__global__ __launch_bounds__(64, 1)
void cfe_kernel(const float* __restrict__ x,   // (T,B,2)
                const float* __restrict__ ps,  // (B,NSTAT)
                float* __restrict__ out)       // (T,B)
{
    const int tid = blockIdx.x * 64 + threadIdx.x;
    const int b   = tid >> 3;     // basin, [0,2048)
    const int m0  = tid & 7;      // handles m0 and m0+8
    if (b >= BATCH) return;

    const float* __restrict__ row = ps + b * NSTAT;

    // ---- per-chain parameters & derived constants ----------------------
    float k1[NCH], k2[NCH], max_soil[NCH], fc_th[NCH], ic[NCH], cc[NCH],
          pc[NCH], lc[NCH], sc_c[NCH], e2[NCH], Km[NCH], Kk[NCH],
          Cgw[NCH], inv_mgw[NCH];

    #pragma unroll
    for (int c = 0; c < NCH; ++c) {
        const int m = m0 + c * 8;
        const float schaake    = row[ 0*NMULC + m] * 0.1f;
        const float smcmax     = row[ 1*NMULC + m] * 0.3f   + 0.3f;
        const float soil_depth = row[ 2*NMULC + m] * 2.5f   + 0.5f;
        const float wltsmc     = row[ 3*NMULC + m] * 0.15f  + 0.05f;
        const float satpsi     = row[ 4*NMULC + m] * 0.49f  + 0.01f;
        const float bb         = row[ 5*NMULC + m] * 10.0f  + 2.0f;
        const float multp      = row[ 6*NMULC + m] * 1900.0f+ 100.0f;
        const float satdk      = row[ 7*NMULC + m] * (1e-4f - 1e-7f) + 1e-7f;
        const float slop       = row[ 8*NMULC + m];
        const float max_gw     = row[ 9*NMULC + m] * 0.49f  + 0.01f;
        Cgw[c]                 = row[10*NMULC + m] * (1e-3f - 1e-6f) + 1e-6f;
        const float expon      = row[11*NMULC + m] * 7.0f   + 1.0f;
        Kk[c]                  = row[12*NMULC + m] * 0.49f  + 0.01f;

        const float inv_sd  = 1.0f / soil_depth;
        const float bud_den = 1.0f / (smcmax - wltsmc + NZ);
        k1[c] = inv_sd * bud_den;
        k2[c] = -wltsmc * bud_den;
        max_soil[c] = smcmax * soil_depth;
        float fc_frac = powf(satpsi * inv_sd, 1.0f / bb);
        fc_frac = fminf(fmaxf(fc_frac, 0.0f), 1.0f);
        fc_th[c] = smcmax * fc_frac * soil_depth;
        ic[c] = 1.0f - expf(-schaake);
        const float sm  = satdk * multp;
        const float sml = sm * slop;
        const float inv_mft = 1.0f / fmaxf(max_soil[c] - fc_th[c], NZ);
        inv_mgw[c] = 1.0f / max_gw;
        cc[c] = inv_mft * (sm + sml);
        pc[c] = sm  * inv_mft;
        lc[c] = sml * inv_mft;
        sc_c[c] = fminf(1.0f, 1.0f / cc[c]);
        e2[c] = expon * 1.442695041f;       // expon * log2(e)
        Km[c] = 1.0f - Kk[c];
    }
    const float inv_nz = 1.0f / NZ;

    // ---- routing weights: per-basin, shared by both chains -------------
    const float rout_a = row[NPHYS*NMULC + 0] * 2.9f;
    const float rout_b = row[NPHYS*NMULC + 1] * 6.5f;
    const float a  = fmaxf(rout_a, 0.0f) + 0.1f;
    const float th = fmaxf(rout_b, 0.0f) + 0.5f;
    float w[LENFC];
    float wsum = 0.0f;
    #pragma unroll
    for (int j = 0; j < LENFC; ++j) {
        const float tj = (float)j + 0.5f;
        w[j] = powf(tj, a - 1.0f) * expf(-tj / th);
        wsum += w[j];
    }
    const float wscale = 1.0f / (wsum * (float)NMULC);
    #pragma unroll
    for (int j = 0; j < LENFC; ++j) w[j] *= wscale;

    // ---- state ----------------------------------------------------------
    float soil[NCH] = {0.05f, 0.05f}, gw[NCH] = {0.01f, 0.01f};
    float n0[NCH] = {NZ, NZ}, n1[NCH] = {NZ, NZ}, n2[NCH] = {NZ, NZ};
    float ring[LENFC];                  // per-basin (chains summed) history
    #pragma unroll
    for (int j = 0; j < LENFC; ++j) ring[j] = 0.0f;

    const float2* __restrict__ xp = (const float2*)x;

    float2 fb0 = xp[0 * BATCH + b];
    float2 fb1 = xp[1 * BATCH + b];
    float2 fb2 = xp[2 * BATCH + b];
    float2 fb3 = xp[3 * BATCH + b];

    float s_prev = 0.0f;

    #pragma unroll 2
    for (int t = 0; t < T_STEPS; ++t) {
        // ---- pipelined DPP reduction + store for step t-1 (off-chain) ---
        {
            const float r = dpp_sum8(s_prev);
            if (t > 0 && m0 == 0) out[(t - 1) * BATCH + b] = r;
        }

        const float p   = fb0.x;
        const float pet = fb0.y;
        fb0 = fb1; fb1 = fb2; fb2 = fb3;
        const int tn = (t + 4 < T_STEPS) ? (t + 4) : (T_STEPS - 1);
        fb3 = xp[tn * BATCH + b];

        // -- shared forcing precompute
        const float et_rain = fminf(p, pet);
        const float p_rem   = p - et_rain;
        const float pet_rem = pet - et_rain;
        const float prem_nz = p_rem + NZ;
        const float prem_sq = p_rem * p_rem;

        // -- two independent chain bodies (compiler interleaves them)
        float qsum = 0.0f;
        #pragma unroll
        for (int c = 0; c < NCH; ++c) {
            float budyko = fmaf(soil[c], k1[c], k2[c]);
            budyko = fminf(fmaxf(budyko, 0.0f), 1.0f);
            const float aet = fminf(pet_rem * budyko, soil[c] - NZ);
            float so = soil[c] - aet;

            const float deficit = max_soil[c] - so;
            const float den     = fmaf(deficit, ic[c], prem_nz);
            const float runoff0 = prem_sq * frcp(den);
            const float infil   = fminf(p_rem - runoff0, deficit);
            const float runoff  = p_rem - infil;
            so += infil;

            const float above = fmaxf(so - fc_th[c], 0.0f);
            const float asc   = fminf(above * sc_c[c], above * above * inv_nz);
            const float lat   = lc[c] * asc;
            so = fmaf(-cc[c], asc, so);
            soil[c] = so;

            float g = fmaf(pc[c], asc, gw[c]);
            const float ratio = fminf(g * inv_mgw[c], 1.0f);
            const float qg0   = fmaf(Cgw[c], __builtin_amdgcn_exp2f(e2[c] * ratio), -Cgw[c]);
            const float qg    = fminf(qg0, g - NZ);
            gw[c] = g - qg;

            const float s0 = n0[c] + lat;           const float s1 = fmaf(Kk[c], s0, n1[c]);
            const float s2 = fmaf(Kk[c], s1, n2[c]); const float o2 = Kk[c] * s2;
            n0[c] = Km[c] * s0; n1[c] = Km[c] * s1; n2[c] = Km[c] * s2;

            qsum += runoff + o2 + qg;
        }

        // -- one ring + one 15-tap conv per basin (conv is linear in q)
        #pragma unroll
        for (int j = LENFC - 1; j > 0; --j) ring[j] = ring[j - 1];
        ring[0] = qsum;
        float c0 = 0.0f, c1 = 0.0f, c2 = 0.0f, c3 = 0.0f;
        #pragma unroll
        for (int j = 0; j < LENFC; j += 4) {
            c0 = fmaf(w[j], ring[j], c0);
            if (j + 1 < LENFC) c1 = fmaf(w[j + 1], ring[j + 1], c1);
            if (j + 2 < LENFC) c2 = fmaf(w[j + 2], ring[j + 2], c2);
            if (j + 3 < LENFC) c3 = fmaf(w[j + 3], ring[j + 3], c3);
        }
        s_prev = (c0 + c1) + (c2 + c3);
    }

    // ---- epilogue --------------------------------------------------------
    {
        const float r = dpp_sum8(s_prev);
        if (m0 == 0) out[(T_STEPS - 1) * BATCH + b] = r;
    }
}

extern "C" void kernel_launch(void* const* d_in, const int* in_sizes, int n_in,
                              void* d_out, int out_size, void* d_ws, size_t ws_size,
                              hipStream_t stream) {
    const float* x_phy      = (const float*)d_in[0];
    const float* phy_static = (const float*)d_in[1];
    float* out = (float*)d_out;

    const int total = BATCH * LPB;              // 16384 threads
    const int block = 64;
    const int grid  = total / block;            // 256 blocks -> 1 per CU
    cfe_kernel<<<grid, block, 0, stream>>>(x_phy, phy_static, out);
}